// Round 3
// baseline (524.266 us; speedup 1.0000x reference)
//
#include <hip/hip_runtime.h>

// ---------------------------------------------------------------------------
// CellVGAE GCN encoder: x -> GCN(512,128)+ReLU -> GCN(128,128)+ReLU
//                         -> {GCN(128,64) mean, GCN(128,64) log_std}
// Round 8:
//  - Latency law from r5/r6/r7: dur x occupancy ~ const; all pipes <15%.
//    Grid (782 blocks = 3/CU) was the occupancy cap, not barriers/LDS.
//  - GEMM: round-5 structure kept (LDS staging, 2 barriers/step, low VGPR)
//    but block tile halved to 32 rows x 128 cols -> grid 1563 (6.1/CU,
//    24.4 waves/CU reachable). Wave tile 32x32 (col quarter per wave):
//    acc 16 VGPR, LDS 20.8 KB. A staged in fragment order (lane-seq,
//    conflict-free); B staging map = round-5 verbatim. MFMA order
//    bit-identical to round 5 => identical numerics.
// ---------------------------------------------------------------------------

using u16 = unsigned short;
typedef __attribute__((ext_vector_type(8))) short short8;
typedef __attribute__((ext_vector_type(4))) short short4v;
typedef __attribute__((ext_vector_type(4))) float f32x4;

__device__ __forceinline__ void split_bf16(float f, u16& hi, u16& lo) {
    unsigned b = __float_as_uint(f);
    hi = (u16)(b >> 16);
    float rem = f - __uint_as_float(b & 0xFFFF0000u);
    lo = (u16)(__float_as_uint(rem) >> 16);
}

// Block-wide mode detect: 1 = int64 edge_index, 0 = int32.
__device__ __forceinline__ int block_mode(const int* __restrict__ ew, int* sflag) {
    if (threadIdx.x == 0) *sflag = 0;
    __syncthreads();
    if (ew[2 * (int)threadIdx.x + 1] != 0) atomicOr(sflag, 1);
    __syncthreads();
    return *sflag ? 0 : 1;
}

// ---- degree count (mode detect inlined) -----------------------------------
__global__ void deg_kernel(const int* __restrict__ ew, int* __restrict__ deg, int E) {
    __shared__ int sflag;
    int mode = block_mode(ew, &sflag);
    int e = blockIdx.x * blockDim.x + threadIdx.x;
    if (e >= E) return;
    int d = mode ? ew[2 * E + 2 * e] : ew[E + e];
    atomicAdd(&deg[d], 1);
}

// ---- exclusive scan over deg -> rowptr, fused dis = rsqrt(deg+1) ----------
__global__ void scan_block_kernel(const int* __restrict__ deg, int* __restrict__ rowptr,
                                  int* __restrict__ aux, float* __restrict__ dis, int N) {
    __shared__ int s[256];
    int i = blockIdx.x * 256 + threadIdx.x;
    int v = (i < N) ? deg[i] : 0;
    if (i < N) dis[i] = rsqrtf((float)v + 1.0f);
    s[threadIdx.x] = v;
    __syncthreads();
    for (int off = 1; off < 256; off <<= 1) {
        int t = (threadIdx.x >= off) ? s[threadIdx.x - off] : 0;
        __syncthreads();
        s[threadIdx.x] += t;
        __syncthreads();
    }
    if (i < N) rowptr[i] = s[threadIdx.x] - v;
    if (threadIdx.x == 255) aux[blockIdx.x] = s[255];
}

__global__ void scan_aux_kernel(int* __restrict__ aux, int nb) {
    __shared__ int s[256];
    int i = threadIdx.x;
    int v = (i < nb) ? aux[i] : 0;
    s[i] = v;
    __syncthreads();
    for (int off = 1; off < 256; off <<= 1) {
        int t = (i >= off) ? s[i - off] : 0;
        __syncthreads();
        s[i] += t;
        __syncthreads();
    }
    if (i < nb) aux[i] = s[i] - v;
}

__global__ void add_offsets_kernel(int* __restrict__ rowptr, const int* __restrict__ aux,
                                   int N, int E) {
    int i = blockIdx.x * 256 + threadIdx.x;
    if (i < N) rowptr[i] += aux[i >> 8];
    if (i == 0) rowptr[N] = E;
}

// ---- CSR fill (mode detect inlined) ---------------------------------------
__global__ void fill_csr_kernel(const int* __restrict__ ew,
                                const int* __restrict__ rowptr, int* __restrict__ cursor,
                                int* __restrict__ csr_src, int E) {
    __shared__ int sflag;
    int mode = block_mode(ew, &sflag);
    int e = blockIdx.x * blockDim.x + threadIdx.x;
    if (e >= E) return;
    int s = mode ? ew[2 * e] : ew[e];
    int d = mode ? ew[2 * E + 2 * e] : ew[E + e];
    int pos = rowptr[d] + atomicAdd(&cursor[d], 1);
    csr_src[pos] = s;
}

// ---- all weight transposed-splits in one kernel ---------------------------
__global__ void conv_all_kernel(const float* __restrict__ W1, const float* __restrict__ W2,
                                const float* __restrict__ Wm, const float* __restrict__ Ws,
                                u16* __restrict__ W1t_hi, u16* __restrict__ W1t_lo,
                                u16* __restrict__ W2t_hi, u16* __restrict__ W2t_lo,
                                u16* __restrict__ Wct_hi, u16* __restrict__ Wct_lo) {
    int idx = blockIdx.x * 256 + threadIdx.x;
    u16 h, l;
    if (idx < 65536) {                 // W1: 512x128 -> [128][512]
        int k = idx >> 7, n = idx & 127;
        split_bf16(W1[idx], h, l);
        W1t_hi[n * 512 + k] = h;
        W1t_lo[n * 512 + k] = l;
    } else if (idx < 81920) {          // W2: 128x128 -> [128][128]
        int t = idx - 65536;
        int k = t >> 7, n = t & 127;
        split_bf16(W2[t], h, l);
        W2t_hi[n * 128 + k] = h;
        W2t_lo[n * 128 + k] = l;
    } else if (idx < 98304) {          // [Wm|Ws]: 128x128 -> [128][128]
        int t = idx - 81920;
        int k = t >> 7, j = t & 127;
        float f = (j < 64) ? Wm[k * 64 + j] : Ws[k * 64 + (j - 64)];
        split_bf16(f, h, l);
        Wct_hi[j * 128 + k] = h;
        Wct_lo[j * 128 + k] = l;
    }
}

// ---- MFMA GEMM: C[N x 128] = A[N x K] @ B[K x 128] (B given split+T) ------
// Block = 32 rows x 128 cols, 4 waves; wave w = 32 rows x cols [w*32,w*32+32).
// Fragment-order LDS tiles (16x16 frag x 32 k), tile stride 520 u16 = 1040 B.
// Frag layout (mfma_f32_16x16x32_bf16, verified): lane L: row/col (L&15),
// k=(L>>4)*8..+8; C/D: col=lane&15, row=(lane>>4)*4+reg.
#define TILE_OFF(t) ((t) * 520)

__global__ __launch_bounds__(256) void gemm_mfma(const float* __restrict__ A,
                                                 const u16* __restrict__ Bt_hi,
                                                 const u16* __restrict__ Bt_lo,
                                                 float* __restrict__ C,
                                                 int N, int K) {
    __shared__ __align__(16) u16 AsH[2 * 520], AsL[2 * 520];   // 32 rows
    __shared__ __align__(16) u16 BsH[8 * 520], BsL[8 * 520];   // 128 cols
    // total 20800 B

    const int tid = threadIdx.x;
    const int w = tid >> 6, lane = tid & 63;
    const int m16 = lane & 15, quad = lane >> 4;
    const int row0 = blockIdx.x * 32;

    // A staging: thread -> (row s_ar in [0,32), 4-float k-chunk s_ac in [0,8))
    // dst in fragment order; consecutive tids (same s_ac) are lane-sequential
    // within each 16-row tile => conflict-free 8B writes.
    const int s_ar = tid & 31;
    const int s_ac = tid >> 5;
    int ar = row0 + s_ar; if (ar > N - 1) ar = N - 1;   // clamp: dup rows ok
    const float* aptr = A + (size_t)ar * K + s_ac * 4;
    const int a_dst = TILE_OFF(s_ar >> 4) + ((s_ac >> 1) * 16 + (s_ar & 15)) * 8
                      + (s_ac & 1) * 4;

    // B staging (round-5 map): thread -> (col, k-half)
    const int s_bc = tid >> 1;                 // 0..127
    const int s_bk = (tid & 1) * 16;           // u16 k offset 0 or 16
    const int b_q0 = (tid & 1) * 2;
    const int b_dst0 = TILE_OFF(s_bc >> 4) + ((s_bc & 15) + 16 * (b_q0 + 0)) * 8;
    const int b_dst1 = TILE_OFF(s_bc >> 4) + ((s_bc & 15) + 16 * (b_q0 + 1)) * 8;
    const u16* bph = Bt_hi + (size_t)s_bc * K + s_bk;
    const u16* bpl = Bt_lo + (size_t)s_bc * K + s_bk;

    const int btile = w * 2;                   // wave's 2 col-tiles (32 cols)

    f32x4 acc[2][2];
#pragma unroll
    for (int i = 0; i < 2; ++i)
#pragma unroll
        for (int j = 0; j < 2; ++j) acc[i][j] = (f32x4)0.f;

    f32x4 av;                                  // A staging reg (4 floats)
    short8 rbh0, rbh1, rbl0, rbl1;             // B staging regs

    const int ksteps = K >> 5;                 // 16 (K=512) or 4 (K=128)

    av = *(const f32x4*)&aptr[0];
    rbh0 = *(const short8*)&bph[0];
    rbh1 = *(const short8*)&bph[8];
    rbl0 = *(const short8*)&bpl[0];
    rbl1 = *(const short8*)&bpl[8];

    for (int ks = 0; ks < ksteps; ++ks) {
        short4v ah4, al4;
#pragma unroll
        for (int q = 0; q < 4; ++q) {
            u16 hh, ll;
            split_bf16(av[q], hh, ll);
            ah4[q] = (short)hh;
            al4[q] = (short)ll;
        }
        __syncthreads();                       // prev frag reads done
        *(short4v*)&AsH[a_dst] = ah4;
        *(short4v*)&AsL[a_dst] = al4;
        *(short8*)&BsH[b_dst0] = rbh0;
        *(short8*)&BsH[b_dst1] = rbh1;
        *(short8*)&BsL[b_dst0] = rbl0;
        *(short8*)&BsL[b_dst1] = rbl1;
        __syncthreads();                       // tile visible

        if (ks + 1 < ksteps) {
            const int k0 = (ks + 1) * 32;
            av = *(const f32x4*)&aptr[k0];
            rbh0 = *(const short8*)&bph[k0];
            rbh1 = *(const short8*)&bph[k0 + 8];
            rbl0 = *(const short8*)&bpl[k0];
            rbl1 = *(const short8*)&bpl[k0 + 8];
        }

        short8 fah[2], fal[2], fbh[2], fbl[2];
#pragma unroll
        for (int i = 0; i < 2; ++i) {
            fah[i] = *(const short8*)&AsH[TILE_OFF(i) + lane * 8];
            fal[i] = *(const short8*)&AsL[TILE_OFF(i) + lane * 8];
        }
#pragma unroll
        for (int j = 0; j < 2; ++j) {
            fbh[j] = *(const short8*)&BsH[TILE_OFF(btile + j) + lane * 8];
            fbl[j] = *(const short8*)&BsL[TILE_OFF(btile + j) + lane * 8];
        }

#pragma unroll
        for (int i = 0; i < 2; ++i)
#pragma unroll
            for (int j = 0; j < 2; ++j) {
                acc[i][j] = __builtin_amdgcn_mfma_f32_16x16x32_bf16(
                    fah[i], fbh[j], acc[i][j], 0, 0, 0);
                acc[i][j] = __builtin_amdgcn_mfma_f32_16x16x32_bf16(
                    fah[i], fbl[j], acc[i][j], 0, 0, 0);
                acc[i][j] = __builtin_amdgcn_mfma_f32_16x16x32_bf16(
                    fal[i], fbh[j], acc[i][j], 0, 0, 0);
            }
    }

    // epilogue: C/D layout col=lane&15, row=quad*4+reg
#pragma unroll
    for (int i = 0; i < 2; ++i) {
#pragma unroll
        for (int r = 0; r < 4; ++r) {
            int gr = row0 + i * 16 + quad * 4 + r;
            if (gr < N) {
#pragma unroll
                for (int j = 0; j < 2; ++j)
                    C[(size_t)gr * 128 + w * 32 + j * 16 + m16] = acc[i][j][r];
            }
        }
    }
}

// ---- propagate (one wave per node, 128 feats = 2/lane), unroll x8 ---------
__global__ __launch_bounds__(256) void propagate_kernel(
    const float* __restrict__ h, const int* __restrict__ rowptr,
    const int* __restrict__ csr_src, const float* __restrict__ dis,
    const float* __restrict__ bias, float* __restrict__ out, int N, int do_relu) {
    int wave = (blockIdx.x * 256 + threadIdx.x) >> 6;
    int lane = threadIdx.x & 63;
    if (wave >= N) return;
    int v = wave;
    int f = lane * 2;
    float dv = dis[v];
    float ax = 0.f, ay = 0.f;
    int beg = rowptr[v], end = rowptr[v + 1];
    int i = beg;
    for (; i + 8 <= end; i += 8) {
        int s[8];
        float ww[8];
        float2 g[8];
#pragma unroll
        for (int u = 0; u < 8; ++u) s[u] = csr_src[i + u];
#pragma unroll
        for (int u = 0; u < 8; ++u) ww[u] = dis[s[u]];
#pragma unroll
        for (int u = 0; u < 8; ++u) g[u] = *(const float2*)&h[(size_t)s[u] * 128 + f];
#pragma unroll
        for (int u = 0; u < 8; ++u) {
            float t = ww[u] * dv;
            ax += t * g[u].x;
            ay += t * g[u].y;
        }
    }
    if (i + 4 <= end) {
        int s[4];
        float ww[4];
        float2 g[4];
#pragma unroll
        for (int u = 0; u < 4; ++u) s[u] = csr_src[i + u];
#pragma unroll
        for (int u = 0; u < 4; ++u) ww[u] = dis[s[u]];
#pragma unroll
        for (int u = 0; u < 4; ++u) g[u] = *(const float2*)&h[(size_t)s[u] * 128 + f];
#pragma unroll
        for (int u = 0; u < 4; ++u) {
            float t = ww[u] * dv;
            ax += t * g[u].x;
            ay += t * g[u].y;
        }
        i += 4;
    }
    for (; i < end; ++i) {
        int s = csr_src[i];
        float ws = dis[s] * dv;
        float2 g = *(const float2*)&h[(size_t)s * 128 + f];
        ax += ws * g.x;
        ay += ws * g.y;
    }
    float2 hv = *(const float2*)&h[(size_t)v * 128 + f];
    ax += dv * dv * hv.x;
    ay += dv * dv * hv.y;
    ax += bias[f];
    ay += bias[f + 1];
    if (do_relu) { ax = fmaxf(ax, 0.f); ay = fmaxf(ay, 0.f); }
    *(float2*)&out[(size_t)v * 128 + f] = make_float2(ax, ay);
}

// ---- final propagate: split into z_mean / z_log_std -----------------------
__global__ void __launch_bounds__(256) propagate_final_kernel(
    const float* __restrict__ h, const int* __restrict__ rowptr,
    const int* __restrict__ csr_src, const float* __restrict__ dis,
    const float* __restrict__ bm, const float* __restrict__ bs,
    float* __restrict__ out, int N) {
    int wave = (blockIdx.x * 256 + threadIdx.x) >> 6;
    int lane = threadIdx.x & 63;
    if (wave >= N) return;
    int v = wave;
    int f = lane * 2;
    float dv = dis[v];
    float ax = 0.f, ay = 0.f;
    int beg = rowptr[v], end = rowptr[v + 1];
    int i = beg;
    for (; i + 8 <= end; i += 8) {
        int s[8];
        float ww[8];
        float2 g[8];
#pragma unroll
        for (int u = 0; u < 8; ++u) s[u] = csr_src[i + u];
#pragma unroll
        for (int u = 0; u < 8; ++u) ww[u] = dis[s[u]];
#pragma unroll
        for (int u = 0; u < 8; ++u) g[u] = *(const float2*)&h[(size_t)s[u] * 128 + f];
#pragma unroll
        for (int u = 0; u < 8; ++u) {
            float t = ww[u] * dv;
            ax += t * g[u].x;
            ay += t * g[u].y;
        }
    }
    if (i + 4 <= end) {
        int s[4];
        float ww[4];
        float2 g[4];
#pragma unroll
        for (int u = 0; u < 4; ++u) s[u] = csr_src[i + u];
#pragma unroll
        for (int u = 0; u < 4; ++u) ww[u] = dis[s[u]];
#pragma unroll
        for (int u = 0; u < 4; ++u) g[u] = *(const float2*)&h[(size_t)s[u] * 128 + f];
#pragma unroll
        for (int u = 0; u < 4; ++u) {
            float t = ww[u] * dv;
            ax += t * g[u].x;
            ay += t * g[u].y;
        }
        i += 4;
    }
    for (; i < end; ++i) {
        int s = csr_src[i];
        float ws = dis[s] * dv;
        float2 g = *(const float2*)&h[(size_t)s * 128 + f];
        ax += ws * g.x;
        ay += ws * g.y;
    }
    float2 hv = *(const float2*)&h[(size_t)v * 128 + f];
    ax += dv * dv * hv.x;
    ay += dv * dv * hv.y;
    if (f < 64) {
        *(float2*)&out[(size_t)v * 64 + f] = make_float2(ax + bm[f], ay + bm[f + 1]);
    } else {
        int g = f - 64;
        *(float2*)&out[(size_t)N * 64 + (size_t)v * 64 + g] =
            make_float2(ax + bs[g], ay + bs[g + 1]);
    }
}

extern "C" void kernel_launch(void* const* d_in, const int* in_sizes, int n_in,
                              void* d_out, int out_size, void* d_ws, size_t ws_size,
                              hipStream_t stream) {
    const float* x  = (const float*)d_in[0];
    const int*   ew = (const int*)d_in[1];
    const float* W1 = (const float*)d_in[2];
    const float* b1 = (const float*)d_in[3];
    const float* W2 = (const float*)d_in[4];
    const float* b2 = (const float*)d_in[5];
    const float* Wm = (const float*)d_in[6];
    const float* bm = (const float*)d_in[7];
    const float* Ws = (const float*)d_in[8];
    const float* bs = (const float*)d_in[9];
    float* out = (float*)d_out;

    const int IN = 512, H = 128;
    const int N = in_sizes[0] / IN;     // 50000
    const int E = in_sizes[1] / 2;      // 800000

    // ---- workspace: ~55.6 MB total (< proven-safe 58.47 MB) ----------------
    char* base = (char*)d_ws;
    size_t off = 0;
    auto alloc = [&](size_t bytes) -> char* {
        char* p = base + off;
        off = (off + bytes + 255) & ~(size_t)255;
        return p;
    };
    char*  degcur  = (char*) alloc(400384);             // deg + cursor (zeroed)
    float* dis     = (float*)alloc((size_t)N * 4);
    int*   rowptr  = (int*)  alloc((size_t)(N + 1) * 4);
    int*   aux     = (int*)  alloc(256 * 4);
    int*   csr_src = (int*)  alloc((size_t)E * 4);
    u16*   W1t_hi  = (u16*)  alloc((size_t)IN * H * 2);
    u16*   W1t_lo  = (u16*)  alloc((size_t)IN * H * 2);
    u16*   W2t_hi  = (u16*)  alloc((size_t)H * H * 2);
    u16*   W2t_lo  = (u16*)  alloc((size_t)H * H * 2);
    u16*   Wct_hi  = (u16*)  alloc((size_t)H * H * 2);
    u16*   Wct_lo  = (u16*)  alloc((size_t)H * H * 2);
    float* hA      = (float*)alloc((size_t)N * H * 4);
    float* hB      = (float*)alloc((size_t)N * H * 4);
    (void)ws_size; (void)n_in; (void)out_size;

    int* deg    = (int*)degcur;
    int* cursor = (int*)(degcur + 200192);

    hipMemsetAsync(degcur, 0, 400384, stream);

    const int eblocks = (E + 255) / 256;
    const int nblocks = (N + 255) / 256;

    conv_all_kernel<<<(98304 + 255) / 256, 256, 0, stream>>>(
        W1, W2, Wm, Ws, W1t_hi, W1t_lo, W2t_hi, W2t_lo, Wct_hi, Wct_lo);
    deg_kernel<<<eblocks, 256, 0, stream>>>(ew, deg, E);
    scan_block_kernel<<<nblocks, 256, 0, stream>>>(deg, rowptr, aux, dis, N);
    scan_aux_kernel<<<1, 256, 0, stream>>>(aux, nblocks);
    add_offsets_kernel<<<nblocks, 256, 0, stream>>>(rowptr, aux, N, E);
    fill_csr_kernel<<<eblocks, 256, 0, stream>>>(ew, rowptr, cursor, csr_src, E);

    // GEMM: 32-row block tiles, 4 waves (each 32 rows x 32 cols)
    const int gblocks = (N + 31) / 32;
    const int pblocks = (N * 64 + 255) / 256;

    gemm_mfma<<<gblocks, 256, 0, stream>>>(x, W1t_hi, W1t_lo, hA, N, IN);
    propagate_kernel<<<pblocks, 256, 0, stream>>>(hA, rowptr, csr_src, dis,
                                                  b1, hB, N, 1);
    gemm_mfma<<<gblocks, 256, 0, stream>>>(hB, W2t_hi, W2t_lo, hA, N, H);
    propagate_kernel<<<pblocks, 256, 0, stream>>>(hA, rowptr, csr_src, dis,
                                                  b2, hB, N, 1);
    gemm_mfma<<<gblocks, 256, 0, stream>>>(hB, Wct_hi, Wct_lo, hA, N, H);
    propagate_final_kernel<<<pblocks, 256, 0, stream>>>(hA, rowptr, csr_src, dis,
                                                        bm, bs, out, N);
}

// Round 5
// 484.725 us; speedup vs baseline: 1.0816x; 1.0816x over previous
//
#include <hip/hip_runtime.h>

// ---------------------------------------------------------------------------
// CellVGAE GCN encoder: x -> GCN(512,128)+ReLU -> GCN(128,128)+ReLU
//                         -> {GCN(128,64) mean, GCN(128,64) log_std}
// Round 10 (= round 9 resubmit; bench infra failed, no counters):
//  - Evidence: all blocks co-resident => gemm dur = single-block K-chain
//    latency; 1.6M bank conflicts traced to B LDS staging writes; B's
//    global gather (per-lane col reads) shatters 128 lines/wave-step
//    inside the barrier-locked chain.
//  - Fix: conv_all emits B in MFMA FRAGMENT ORDER; gemm loads B frags
//    direct from global (lane*16B dense, L2-hot, no LDS, no barrier dep),
//    issued at step top so cvt+barrier+LDS-write covers latency.
//    A path, loop structure, MFMA order = round-5 verbatim -> identical
//    numerics. LDS 25 KB -> 8.3 KB.
// ---------------------------------------------------------------------------

using u16 = unsigned short;
typedef __attribute__((ext_vector_type(8))) short short8;
typedef __attribute__((ext_vector_type(4))) float f32x4;

__device__ __forceinline__ void split_bf16(float f, u16& hi, u16& lo) {
    unsigned b = __float_as_uint(f);
    hi = (u16)(b >> 16);
    float rem = f - __uint_as_float(b & 0xFFFF0000u);
    lo = (u16)(__float_as_uint(rem) >> 16);
}

// Block-wide mode detect: 1 = int64 edge_index, 0 = int32.
__device__ __forceinline__ int block_mode(const int* __restrict__ ew, int* sflag) {
    if (threadIdx.x == 0) *sflag = 0;
    __syncthreads();
    if (ew[2 * (int)threadIdx.x + 1] != 0) atomicOr(sflag, 1);
    __syncthreads();
    return *sflag ? 0 : 1;
}

// ---- degree count (mode detect inlined) -----------------------------------
__global__ void deg_kernel(const int* __restrict__ ew, int* __restrict__ deg, int E) {
    __shared__ int sflag;
    int mode = block_mode(ew, &sflag);
    int e = blockIdx.x * blockDim.x + threadIdx.x;
    if (e >= E) return;
    int d = mode ? ew[2 * E + 2 * e] : ew[E + e];
    atomicAdd(&deg[d], 1);
}

// ---- exclusive scan over deg -> rowptr, fused dis = rsqrt(deg+1) ----------
__global__ void scan_block_kernel(const int* __restrict__ deg, int* __restrict__ rowptr,
                                  int* __restrict__ aux, float* __restrict__ dis, int N) {
    __shared__ int s[256];
    int i = blockIdx.x * 256 + threadIdx.x;
    int v = (i < N) ? deg[i] : 0;
    if (i < N) dis[i] = rsqrtf((float)v + 1.0f);
    s[threadIdx.x] = v;
    __syncthreads();
    for (int off = 1; off < 256; off <<= 1) {
        int t = (threadIdx.x >= off) ? s[threadIdx.x - off] : 0;
        __syncthreads();
        s[threadIdx.x] += t;
        __syncthreads();
    }
    if (i < N) rowptr[i] = s[threadIdx.x] - v;
    if (threadIdx.x == 255) aux[blockIdx.x] = s[255];
}

__global__ void scan_aux_kernel(int* __restrict__ aux, int nb) {
    __shared__ int s[256];
    int i = threadIdx.x;
    int v = (i < nb) ? aux[i] : 0;
    s[i] = v;
    __syncthreads();
    for (int off = 1; off < 256; off <<= 1) {
        int t = (i >= off) ? s[i - off] : 0;
        __syncthreads();
        s[i] += t;
        __syncthreads();
    }
    if (i < nb) aux[i] = s[i] - v;
}

__global__ void add_offsets_kernel(int* __restrict__ rowptr, const int* __restrict__ aux,
                                   int N, int E) {
    int i = blockIdx.x * 256 + threadIdx.x;
    if (i < N) rowptr[i] += aux[i >> 8];
    if (i == 0) rowptr[N] = E;
}

// ---- CSR fill (mode detect inlined) ---------------------------------------
__global__ void fill_csr_kernel(const int* __restrict__ ew,
                                const int* __restrict__ rowptr, int* __restrict__ cursor,
                                int* __restrict__ csr_src, int E) {
    __shared__ int sflag;
    int mode = block_mode(ew, &sflag);
    int e = blockIdx.x * blockDim.x + threadIdx.x;
    if (e >= E) return;
    int s = mode ? ew[2 * e] : ew[e];
    int d = mode ? ew[2 * E + 2 * e] : ew[E + e];
    int pos = rowptr[d] + atomicAdd(&cursor[d], 1);
    csr_src[pos] = s;
}

// ---- weights -> MFMA-fragment-order bf16 hi/lo splits ---------------------
// Frag layout (mfma_f32_16x16x32_bf16): tile t (16 cols), step ks (32 k),
// lane L, elem q:  value = hi/lo(B[k][col]), col = t*16+(L&15),
// k = ks*32+(L>>4)*8+q.  Stored at ((t*ksteps+ks)*64+L)*8+q.
__global__ void conv_all_kernel(const float* __restrict__ W1, const float* __restrict__ W2,
                                const float* __restrict__ Wm, const float* __restrict__ Ws,
                                u16* __restrict__ B1h, u16* __restrict__ B1l,
                                u16* __restrict__ B2h, u16* __restrict__ B2l,
                                u16* __restrict__ Bch, u16* __restrict__ Bcl) {
    int idx = blockIdx.x * 256 + threadIdx.x;
    u16 h, l;
    if (idx < 65536) {                 // W1: 512x128, ksteps=16
        int t = idx >> 13;             // /(16*512)
        int ks = (idx >> 9) & 15;
        int L = (idx >> 3) & 63;
        int q = idx & 7;
        int col = t * 16 + (L & 15);
        int k = ks * 32 + (L >> 4) * 8 + q;
        split_bf16(W1[k * 128 + col], h, l);
        B1h[idx] = h;
        B1l[idx] = l;
    } else if (idx < 81920) {          // W2: 128x128, ksteps=4
        int o = idx - 65536;
        int t = o >> 11;               // /(4*512)
        int ks = (o >> 9) & 3;
        int L = (o >> 3) & 63;
        int q = o & 7;
        int col = t * 16 + (L & 15);
        int k = ks * 32 + (L >> 4) * 8 + q;
        split_bf16(W2[k * 128 + col], h, l);
        B2h[o] = h;
        B2l[o] = l;
    } else if (idx < 98304) {          // [Wm|Ws]: 128x128, ksteps=4
        int o = idx - 81920;
        int t = o >> 11;
        int ks = (o >> 9) & 3;
        int L = (o >> 3) & 63;
        int q = o & 7;
        int col = t * 16 + (L & 15);
        int k = ks * 32 + (L >> 4) * 8 + q;
        float f = (col < 64) ? Wm[k * 64 + col] : Ws[k * 64 + (col - 64)];
        split_bf16(f, h, l);
        Bch[o] = h;
        Bcl[o] = l;
    }
}

// ---- MFMA GEMM: C[N x 128] = A[N x K] @ B[K x 128] (B in frag order) ------
// Block 64 rows x 128 cols, 4 waves (2 row x 2 col). A via LDS (r5 map,
// lane-sequential, conflict-free); B frags direct from global (dense,
// L2-hot). Frag: lane L: row/col (L&15), k=(L>>4)*8..+8;
// C/D: col=lane&15, row=(lane>>4)*4+reg.
#define TILE_OFF(t) ((t) * 520)

__global__ __launch_bounds__(256) void gemm_mfma(const float* __restrict__ A,
                                                 const u16* __restrict__ Bfh,
                                                 const u16* __restrict__ Bfl,
                                                 float* __restrict__ C,
                                                 int N, int K) {
    __shared__ __align__(16) u16 AsH[4 * 520], AsL[4 * 520];   // 8.3 KB

    const int tid = threadIdx.x;
    const int w = tid >> 6, lane = tid & 63;
    const int m16 = lane & 15, quad = lane >> 4;
    const int row0 = blockIdx.x * 64;

    // A staging (r5 map): wave w stages rows w*16..w*16+15
    const int s_ar = w * 16 + (lane & 15);
    const int s_ak = (lane >> 4) * 8;
    const int a_dst = TILE_OFF(w) + lane * 8;

    // compute: wave tile = 32 rows x 64 cols
    const int R = (w >> 1) * 32, Cc = (w & 1) * 64;
    const int atile = (w >> 1) * 2;            // + i (0..1)
    const int btile = (w & 1) * 4;             // + j (0..3)

    const int ksteps = K >> 5;
    const u16* bfh = Bfh + ((size_t)btile * ksteps) * 512 + lane * 8;
    const u16* bfl = Bfl + ((size_t)btile * ksteps) * 512 + lane * 8;

    f32x4 acc[2][4];
#pragma unroll
    for (int i = 0; i < 2; ++i)
#pragma unroll
        for (int j = 0; j < 4; ++j) acc[i][j] = (f32x4)0.f;

    const int grow = row0 + s_ar;
    const bool ok = (grow < N);
    const float* aptr = A + (size_t)grow * K + s_ak;

    float av[8];
    {
        f32x4 v0 = (f32x4)0.f, v1 = (f32x4)0.f;
        if (ok) { v0 = *(const f32x4*)&aptr[0]; v1 = *(const f32x4*)&aptr[4]; }
#pragma unroll
        for (int q = 0; q < 4; ++q) { av[q] = v0[q]; av[4 + q] = v1[q]; }
    }

    for (int ks = 0; ks < ksteps; ++ks) {
        // B frag loads first: dense lane*16B, L2-hot; latency covered by
        // cvt + barrier + LDS writes below.
        short8 fbh[4], fbl[4];
#pragma unroll
        for (int j = 0; j < 4; ++j) {
            fbh[j] = *(const short8*)(bfh + (size_t)(j * ksteps + ks) * 512);
            fbl[j] = *(const short8*)(bfl + (size_t)(j * ksteps + ks) * 512);
        }

        short8 ah, al;
#pragma unroll
        for (int q = 0; q < 8; ++q) {
            u16 h, l;
            split_bf16(av[q], h, l);
            ah[q] = (short)h;
            al[q] = (short)l;
        }
        __syncthreads();
        *(short8*)&AsH[a_dst] = ah;
        *(short8*)&AsL[a_dst] = al;
        __syncthreads();

        if (ks + 1 < ksteps) {
            const int k0 = (ks + 1) * 32;
            f32x4 v0 = (f32x4)0.f, v1 = (f32x4)0.f;
            if (ok) { v0 = *(const f32x4*)&aptr[k0]; v1 = *(const f32x4*)&aptr[k0 + 4]; }
#pragma unroll
            for (int q = 0; q < 4; ++q) { av[q] = v0[q]; av[4 + q] = v1[q]; }
        }

        short8 fah[2], fal[2];
#pragma unroll
        for (int i = 0; i < 2; ++i) {
            fah[i] = *(const short8*)&AsH[TILE_OFF(atile + i) + lane * 8];
            fal[i] = *(const short8*)&AsL[TILE_OFF(atile + i) + lane * 8];
        }

#pragma unroll
        for (int i = 0; i < 2; ++i)
#pragma unroll
            for (int j = 0; j < 4; ++j) {
                acc[i][j] = __builtin_amdgcn_mfma_f32_16x16x32_bf16(
                    fah[i], fbh[j], acc[i][j], 0, 0, 0);
                acc[i][j] = __builtin_amdgcn_mfma_f32_16x16x32_bf16(
                    fah[i], fbl[j], acc[i][j], 0, 0, 0);
                acc[i][j] = __builtin_amdgcn_mfma_f32_16x16x32_bf16(
                    fal[i], fbh[j], acc[i][j], 0, 0, 0);
            }
    }

    // epilogue: C/D layout col=lane&15, row=quad*4+reg
#pragma unroll
    for (int i = 0; i < 2; ++i) {
#pragma unroll
        for (int r = 0; r < 4; ++r) {
            int gr = row0 + R + i * 16 + quad * 4 + r;
            if (gr < N) {
#pragma unroll
                for (int j = 0; j < 4; ++j)
                    C[(size_t)gr * 128 + Cc + j * 16 + m16] = acc[i][j][r];
            }
        }
    }
}

// ---- propagate (one wave per node, 128 feats = 2/lane), unroll x8 ---------
__global__ __launch_bounds__(256) void propagate_kernel(
    const float* __restrict__ h, const int* __restrict__ rowptr,
    const int* __restrict__ csr_src, const float* __restrict__ dis,
    const float* __restrict__ bias, float* __restrict__ out, int N, int do_relu) {
    int wave = (blockIdx.x * 256 + threadIdx.x) >> 6;
    int lane = threadIdx.x & 63;
    if (wave >= N) return;
    int v = wave;
    int f = lane * 2;
    float dv = dis[v];
    float ax = 0.f, ay = 0.f;
    int beg = rowptr[v], end = rowptr[v + 1];
    int i = beg;
    for (; i + 8 <= end; i += 8) {
        int s[8];
        float ww[8];
        float2 g[8];
#pragma unroll
        for (int u = 0; u < 8; ++u) s[u] = csr_src[i + u];
#pragma unroll
        for (int u = 0; u < 8; ++u) ww[u] = dis[s[u]];
#pragma unroll
        for (int u = 0; u < 8; ++u) g[u] = *(const float2*)&h[(size_t)s[u] * 128 + f];
#pragma unroll
        for (int u = 0; u < 8; ++u) {
            float t = ww[u] * dv;
            ax += t * g[u].x;
            ay += t * g[u].y;
        }
    }
    if (i + 4 <= end) {
        int s[4];
        float ww[4];
        float2 g[4];
#pragma unroll
        for (int u = 0; u < 4; ++u) s[u] = csr_src[i + u];
#pragma unroll
        for (int u = 0; u < 4; ++u) ww[u] = dis[s[u]];
#pragma unroll
        for (int u = 0; u < 4; ++u) g[u] = *(const float2*)&h[(size_t)s[u] * 128 + f];
#pragma unroll
        for (int u = 0; u < 4; ++u) {
            float t = ww[u] * dv;
            ax += t * g[u].x;
            ay += t * g[u].y;
        }
        i += 4;
    }
    for (; i < end; ++i) {
        int s = csr_src[i];
        float ws = dis[s] * dv;
        float2 g = *(const float2*)&h[(size_t)s * 128 + f];
        ax += ws * g.x;
        ay += ws * g.y;
    }
    float2 hv = *(const float2*)&h[(size_t)v * 128 + f];
    ax += dv * dv * hv.x;
    ay += dv * dv * hv.y;
    ax += bias[f];
    ay += bias[f + 1];
    if (do_relu) { ax = fmaxf(ax, 0.f); ay = fmaxf(ay, 0.f); }
    *(float2*)&out[(size_t)v * 128 + f] = make_float2(ax, ay);
}

// ---- final propagate: split into z_mean / z_log_std -----------------------
__global__ void __launch_bounds__(256) propagate_final_kernel(
    const float* __restrict__ h, const int* __restrict__ rowptr,
    const int* __restrict__ csr_src, const float* __restrict__ dis,
    const float* __restrict__ bm, const float* __restrict__ bs,
    float* __restrict__ out, int N) {
    int wave = (blockIdx.x * 256 + threadIdx.x) >> 6;
    int lane = threadIdx.x & 63;
    if (wave >= N) return;
    int v = wave;
    int f = lane * 2;
    float dv = dis[v];
    float ax = 0.f, ay = 0.f;
    int beg = rowptr[v], end = rowptr[v + 1];
    int i = beg;
    for (; i + 8 <= end; i += 8) {
        int s[8];
        float ww[8];
        float2 g[8];
#pragma unroll
        for (int u = 0; u < 8; ++u) s[u] = csr_src[i + u];
#pragma unroll
        for (int u = 0; u < 8; ++u) ww[u] = dis[s[u]];
#pragma unroll
        for (int u = 0; u < 8; ++u) g[u] = *(const float2*)&h[(size_t)s[u] * 128 + f];
#pragma unroll
        for (int u = 0; u < 8; ++u) {
            float t = ww[u] * dv;
            ax += t * g[u].x;
            ay += t * g[u].y;
        }
    }
    if (i + 4 <= end) {
        int s[4];
        float ww[4];
        float2 g[4];
#pragma unroll
        for (int u = 0; u < 4; ++u) s[u] = csr_src[i + u];
#pragma unroll
        for (int u = 0; u < 4; ++u) ww[u] = dis[s[u]];
#pragma unroll
        for (int u = 0; u < 4; ++u) g[u] = *(const float2*)&h[(size_t)s[u] * 128 + f];
#pragma unroll
        for (int u = 0; u < 4; ++u) {
            float t = ww[u] * dv;
            ax += t * g[u].x;
            ay += t * g[u].y;
        }
        i += 4;
    }
    for (; i < end; ++i) {
        int s = csr_src[i];
        float ws = dis[s] * dv;
        float2 g = *(const float2*)&h[(size_t)s * 128 + f];
        ax += ws * g.x;
        ay += ws * g.y;
    }
    float2 hv = *(const float2*)&h[(size_t)v * 128 + f];
    ax += dv * dv * hv.x;
    ay += dv * dv * hv.y;
    if (f < 64) {
        *(float2*)&out[(size_t)v * 64 + f] = make_float2(ax + bm[f], ay + bm[f + 1]);
    } else {
        int g = f - 64;
        *(float2*)&out[(size_t)N * 64 + (size_t)v * 64 + g] =
            make_float2(ax + bs[g], ay + bs[g + 1]);
    }
}

extern "C" void kernel_launch(void* const* d_in, const int* in_sizes, int n_in,
                              void* d_out, int out_size, void* d_ws, size_t ws_size,
                              hipStream_t stream) {
    const float* x  = (const float*)d_in[0];
    const int*   ew = (const int*)d_in[1];
    const float* W1 = (const float*)d_in[2];
    const float* b1 = (const float*)d_in[3];
    const float* W2 = (const float*)d_in[4];
    const float* b2 = (const float*)d_in[5];
    const float* Wm = (const float*)d_in[6];
    const float* bm = (const float*)d_in[7];
    const float* Ws = (const float*)d_in[8];
    const float* bs = (const float*)d_in[9];
    float* out = (float*)d_out;

    const int IN = 512, H = 128;
    const int N = in_sizes[0] / IN;     // 50000
    const int E = in_sizes[1] / 2;      // 800000

    // ---- workspace: ~55.6 MB total (< proven-safe 58.47 MB) ----------------
    char* base = (char*)d_ws;
    size_t off = 0;
    auto alloc = [&](size_t bytes) -> char* {
        char* p = base + off;
        off = (off + bytes + 255) & ~(size_t)255;
        return p;
    };
    char*  degcur  = (char*) alloc(400384);             // deg + cursor (zeroed)
    float* dis     = (float*)alloc((size_t)N * 4);
    int*   rowptr  = (int*)  alloc((size_t)(N + 1) * 4);
    int*   aux     = (int*)  alloc(256 * 4);
    int*   csr_src = (int*)  alloc((size_t)E * 4);
    u16*   B1h     = (u16*)  alloc((size_t)IN * H * 2);
    u16*   B1l     = (u16*)  alloc((size_t)IN * H * 2);
    u16*   B2h     = (u16*)  alloc((size_t)H * H * 2);
    u16*   B2l     = (u16*)  alloc((size_t)H * H * 2);
    u16*   Bch     = (u16*)  alloc((size_t)H * H * 2);
    u16*   Bcl     = (u16*)  alloc((size_t)H * H * 2);
    float* hA      = (float*)alloc((size_t)N * H * 4);
    float* hB      = (float*)alloc((size_t)N * H * 4);
    (void)ws_size; (void)n_in; (void)out_size;

    int* deg    = (int*)degcur;
    int* cursor = (int*)(degcur + 200192);

    hipMemsetAsync(degcur, 0, 400384, stream);

    const int eblocks = (E + 255) / 256;
    const int nblocks = (N + 255) / 256;

    conv_all_kernel<<<(98304 + 255) / 256, 256, 0, stream>>>(
        W1, W2, Wm, Ws, B1h, B1l, B2h, B2l, Bch, Bcl);
    deg_kernel<<<eblocks, 256, 0, stream>>>(ew, deg, E);
    scan_block_kernel<<<nblocks, 256, 0, stream>>>(deg, rowptr, aux, dis, N);
    scan_aux_kernel<<<1, 256, 0, stream>>>(aux, nblocks);
    add_offsets_kernel<<<nblocks, 256, 0, stream>>>(rowptr, aux, N, E);
    fill_csr_kernel<<<eblocks, 256, 0, stream>>>(ew, rowptr, cursor, csr_src, E);

    // GEMM: 64-row block tiles, 4 waves (2 row x 2 col sub-tiles)
    const int gblocks = (N + 63) / 64;
    const int pblocks = (N * 64 + 255) / 256;

    gemm_mfma<<<gblocks, 256, 0, stream>>>(x, B1h, B1l, hA, N, IN);
    propagate_kernel<<<pblocks, 256, 0, stream>>>(hA, rowptr, csr_src, dis,
                                                  b1, hB, N, 1);
    gemm_mfma<<<gblocks, 256, 0, stream>>>(hB, B2h, B2l, hA, N, H);
    propagate_kernel<<<pblocks, 256, 0, stream>>>(hA, rowptr, csr_src, dis,
                                                  b2, hB, N, 1);
    gemm_mfma<<<gblocks, 256, 0, stream>>>(hB, Bch, Bcl, hA, N, H);
    propagate_final_kernel<<<pblocks, 256, 0, stream>>>(hA, rowptr, csr_src, dis,
                                                        bm, bs, out, N);
}